// Round 8
// baseline (187.060 us; speedup 1.0000x reference)
//
#include <hip/hip_runtime.h>
#include <math.h>

// Problem constants (fixed by reference setup_inputs)
#define NTOT 100
#define NQ   75
#define NP   25
#define CC   128
#define TT   8
#define VV   25
#define NCLS 5
#define NSUP 5
#define NQRY 15
#define ROW  (TT*VV*CC)   // 25600 floats per sample
#define TILE (VV*CC)      // 3200 floats per (n,t)
#define ROWS_Q 20000
#define ROWS_S 5000
#define RB_Q 625
#define RB_S 157

typedef __attribute__((ext_vector_type(8))) short short8;
typedef __attribute__((ext_vector_type(16))) float f32x16;

typedef union { uint4 u4; short8 s8; } pk_t;

__device__ __forceinline__ ushort f2bf(float f) {
    uint u = __float_as_uint(f);
    u += 0x7FFFu + ((u >> 16) & 1u);   // RNE
    return (ushort)(u >> 16);
}
__device__ __forceinline__ float bf2f(uint u16v) {
    return __uint_as_float(u16v << 16);
}
__device__ __forceinline__ uint pkbf(float a, float b) {
    return (uint)f2bf(a) | ((uint)f2bf(b) << 16);
}

// ============ kernel 1: fused gather + projections (replaces prep+proj) ============
// blocks 0..156 : Q = cat@Wq+bq  (625 rowblocks of 32 tv-rows; also writes catC)
// blocks 157..196: K = supp@Wk+bk ; V = (supp@Wv+bv)@Wo  (157 rowblocks)
// Each block: inline rank-sort -> per-lane src; gathers its rows straight from
// input into A-frags (registers); W B-frags built in LDS from global.
__global__ __launch_bounds__(256) void k_proj(
    const float* __restrict__ input, const int* __restrict__ target,
    const float* __restrict__ Wq, const float* __restrict__ Wk,
    const float* __restrict__ Wv, const float* __restrict__ Wo,
    const float* __restrict__ bq, const float* __restrict__ bk,
    const float* __restrict__ bv,
    ushort* __restrict__ catC, ushort* __restrict__ Qf,
    ushort* __restrict__ Kf, ushort* __restrict__ Vf,
    int* __restrict__ counter) {
    __shared__ ushort WfragLDS[16384];   // 32 KB: current W matrix as B-frags
    __shared__ ushort VtFrag[16384];     // 32 KB: Vt as A-frags (also sort scratch)

    int b = blockIdx.x, tid = threadIdx.x;
    int w = tid >> 6, lane = tid & 63, half = lane >> 5, l31 = lane & 31;

    if (b == 0 && tid == 0) *counter = 0;   // ticket for k_dist_loss

    // ---- inline stable rank-sort (scratch aliased in VtFrag) ----
    int* iscr = (int*)VtFrag;
    if (tid < NTOT) iscr[tid] = target[tid];
    __syncthreads();
    if (tid < NTOT) {
        int ti = iscr[tid], rank = 0;
        for (int j = 0; j < NTOT; ++j) {
            int tj = iscr[j];
            rank += (tj < ti) || (tj == ti && j < tid);
        }
        iscr[128 + rank] = tid;
    }
    __syncthreads();

    bool isQ = b < 157;
    int rowblk = isQ ? (b * 4 + w) : ((b - 157) * 4 + w);
    int nrb = isQ ? RB_Q : RB_S;
    bool act = rowblk < nrb;
    int rlimit = isQ ? ROWS_Q : ROWS_S;
    int grow = rowblk * 32 + l31;
    int growc = grow < rlimit ? grow : rlimit - 1;   // clamp pad/inactive lanes
    int n = growc / 200;
    int tv = growc - n * 200;
    int src;
    {
        int nn = isQ ? n : (NQ + n);
        if (nn < NQ) { int m = nn / NQRY, qq = nn - m * NQRY; src = iscr[128 + m * 20 + NSUP + qq]; }
        else         { int i2 = nn - NQ; int m = i2 / NSUP, s = i2 - m * NSUP; src = iscr[128 + m * 20 + s]; }
    }
    __syncthreads();   // src extracted; VtFrag free for reuse

    // ---- gather A-frags from input (per-lane strided dwords) ----
    // af[ks] holds A[row=l31][c = ks*16 + half*8 + j], source addr src*ROW + c*200 + tv
    const float* inp = input + (size_t)src * ROW + tv;
    short8 af[8];
    #pragma unroll
    for (int ks = 0; ks < 8; ++ks) {
        float f0 = inp[(ks * 16 + half * 8 + 0) * 200];
        float f1 = inp[(ks * 16 + half * 8 + 1) * 200];
        float f2 = inp[(ks * 16 + half * 8 + 2) * 200];
        float f3 = inp[(ks * 16 + half * 8 + 3) * 200];
        float f4 = inp[(ks * 16 + half * 8 + 4) * 200];
        float f5 = inp[(ks * 16 + half * 8 + 5) * 200];
        float f6 = inp[(ks * 16 + half * 8 + 6) * 200];
        float f7 = inp[(ks * 16 + half * 8 + 7) * 200];
        pk_t u;
        u.u4 = make_uint4(pkbf(f0, f1), pkbf(f2, f3), pkbf(f4, f5), pkbf(f6, f7));
        af[ks] = u.s8;
    }

    // ---- build W B-frags in LDS from a global fp32 matrix ----
    #define BUILDW(W) do {                                                       \
        for (int o = tid; o < 2048; o += 256) {                                  \
            int k8 = o >> 7, c = o & 127;                                        \
            uint4 pk;                                                            \
            pk.x = pkbf((W)[(k8*8+0)*128 + c], (W)[(k8*8+1)*128 + c]);           \
            pk.y = pkbf((W)[(k8*8+2)*128 + c], (W)[(k8*8+3)*128 + c]);           \
            pk.z = pkbf((W)[(k8*8+4)*128 + c], (W)[(k8*8+5)*128 + c]);           \
            pk.w = pkbf((W)[(k8*8+6)*128 + c], (W)[(k8*8+7)*128 + c]);           \
            int dst = (((c >> 5) * 8 + (k8 >> 1)) * 64 + ((c & 31) + 32 * (k8 & 1))) * 8; \
            *(uint4*)(WfragLDS + dst) = pk;                                      \
        }                                                                        \
    } while (0)

    if (isQ) {
        BUILDW(Wq);
        __syncthreads();
        #pragma unroll
        for (int ct = 0; ct < 4; ++ct) {
            if (!act) continue;
            f32x16 Cm;
            #pragma unroll
            for (int r = 0; r < 16; ++r) Cm[r] = 0.f;
            const ushort* bp = WfragLDS + ct * 8 * 512 + lane * 8;
            #pragma unroll
            for (int ks = 0; ks < 8; ++ks) {
                short8 bf_ = *(const short8*)(bp + ks * 512);
                Cm = __builtin_amdgcn_mfma_f32_32x32x16_bf16(af[ks], bf_, Cm, 0, 0, 0);
            }
            float bcol = bq[ct * 32 + l31];
            #pragma unroll
            for (int r = 0; r < 16; ++r) {
                int row = rowblk * 32 + (r & 3) + 8 * (r >> 2) + 4 * half;
                if (row < ROWS_Q) {
                    int c = ct * 32 + l31;
                    int st = row / 25, vv = row - st * 25;
                    size_t dst = (((size_t)st * 8 + (c >> 4)) * 64 + (vv + 32 * ((c >> 3) & 1))) * 8 + (c & 7);
                    Qf[dst] = f2bf(Cm[r] + bcol);
                }
            }
        }
        // catC bf16 [row][c] straight from A-frags
        if (act) {
            ushort* cc = catC + (size_t)grow * 128 + half * 8;
            #pragma unroll
            for (int ks = 0; ks < 8; ++ks)
                *(short8*)(cc + ks * 16) = af[ks];
        }
    } else {
        // ---- K ----
        BUILDW(Wk);
        __syncthreads();
        #pragma unroll
        for (int ct = 0; ct < 4; ++ct) {
            if (!act) continue;
            f32x16 Cm;
            #pragma unroll
            for (int r = 0; r < 16; ++r) Cm[r] = 0.f;
            const ushort* bp = WfragLDS + ct * 8 * 512 + lane * 8;
            #pragma unroll
            for (int ks = 0; ks < 8; ++ks) {
                short8 bf_ = *(const short8*)(bp + ks * 512);
                Cm = __builtin_amdgcn_mfma_f32_32x32x16_bf16(af[ks], bf_, Cm, 0, 0, 0);
            }
            float bcol = bk[ct * 32 + l31];
            #pragma unroll
            for (int r = 0; r < 16; ++r) {
                int row = rowblk * 32 + (r & 3) + 8 * (r >> 2) + 4 * half;
                if (row < ROWS_S) {
                    int c = ct * 32 + l31;
                    int st = row / 25, vv = row - st * 25;
                    size_t dst = (((size_t)st * 8 + (c >> 4)) * 64 + (vv + 32 * ((c >> 3) & 1))) * 8 + (c & 7);
                    Kf[dst] = f2bf(Cm[r] + bcol);
                }
            }
        }
        __syncthreads();   // all waves done reading Wk frags
        // ---- Vt = supp@Wv + bv -> A-frags in VtFrag (per-wave region) ----
        BUILDW(Wv);
        __syncthreads();
        #pragma unroll
        for (int ct = 0; ct < 4; ++ct) {
            if (!act) continue;
            f32x16 Cm;
            #pragma unroll
            for (int r = 0; r < 16; ++r) Cm[r] = 0.f;
            const ushort* bp = WfragLDS + ct * 8 * 512 + lane * 8;
            #pragma unroll
            for (int ks = 0; ks < 8; ++ks) {
                short8 bf_ = *(const short8*)(bp + ks * 512);
                Cm = __builtin_amdgcn_mfma_f32_32x32x16_bf16(af[ks], bf_, Cm, 0, 0, 0);
            }
            float bcol = bv[ct * 32 + l31];
            int c = ct * 32 + l31;
            int ks2 = c >> 4, lh = (c >> 3) & 1, j2 = c & 7;
            #pragma unroll
            for (int r = 0; r < 16; ++r) {
                int rowLocal = (r & 3) + 8 * (r >> 2) + 4 * half;
                VtFrag[w * 4096 + ks2 * 512 + (rowLocal + 32 * lh) * 8 + j2] = f2bf(Cm[r] + bcol);
            }
        }
        __syncthreads();   // all waves done reading Wv frags
        // ---- V = Vt @ Wo -> Vf frags ----
        BUILDW(Wo);
        __syncthreads();
        short8 a2[8];
        if (act) {
            #pragma unroll
            for (int ks = 0; ks < 8; ++ks)
                a2[ks] = *(const short8*)(VtFrag + w * 4096 + ks * 512 + lane * 8);
        }
        #pragma unroll
        for (int ct = 0; ct < 4; ++ct) {
            if (!act) continue;
            f32x16 Cm;
            #pragma unroll
            for (int r = 0; r < 16; ++r) Cm[r] = 0.f;
            const ushort* bp = WfragLDS + ct * 8 * 512 + lane * 8;
            #pragma unroll
            for (int ks = 0; ks < 8; ++ks) {
                short8 bf_ = *(const short8*)(bp + ks * 512);
                Cm = __builtin_amdgcn_mfma_f32_32x32x16_bf16(a2[ks], bf_, Cm, 0, 0, 0);
            }
            #pragma unroll
            for (int r = 0; r < 16; ++r) {
                int row = rowblk * 32 + (r & 3) + 8 * (r >> 2) + 4 * half;
                if (row < ROWS_S) {
                    int c = ct * 32 + l31;
                    int tile = row / 25, vv = row - tile * 25;
                    size_t dst = ((((size_t)tile * 4 + ct) * 2 + (vv >> 4)) * 64
                                  + ((c & 31) + 32 * ((vv & 15) >> 3))) * 8 + (vv & 7);
                    Vf[dst] = f2bf(Cm[r]);
                }
            }
        }
    }
    #undef BUILDW
}

// ============ kernel 2: MFMA fused attention + residual + LN ============
// (byte-identical to R7: 800 blocks, shuffle-based P transpose, no pipelining)
__global__ __launch_bounds__(256, 2) void k_attn(
    const ushort* __restrict__ Qf, const ushort* __restrict__ Kf,
    const ushort* __restrict__ Vf, const ushort* __restrict__ catC,
    const float* __restrict__ bo, float* __restrict__ att) {
    __shared__ float catb[25 * 129];
    __shared__ float red[2][50][65];
    __shared__ ushort qls[4096];

    int pair = blockIdx.x;                    // n*8 + t
    int t = pair & 7;
    int tid = threadIdx.x;
    int wv = tid >> 6, lane = tid & 63;
    int q = lane & 31, half = lane >> 5;

    {
        const uint* cc = (const uint*)catC + (size_t)pair * 1600;
        for (int i2 = tid; i2 < 1600; i2 += 256) {
            uint u = cc[i2];
            int r = i2 >> 6, c2 = (i2 & 63) * 2;
            catb[r * 129 + c2]     = bf2f(u & 0xffffu) + bo[c2];
            catb[r * 129 + c2 + 1] = bf2f(u >> 16) + bo[c2 + 1];
        }
    }
    {
        const uint* qp = (const uint*)(Qf + (size_t)pair * 4096);
        uint* ql = (uint*)qls;
        for (int i2 = tid; i2 < 2048; i2 += 256) ql[i2] = qp[i2];
    }
    __syncthreads();

    int qc = q < 25 ? q : 24;
    float attsum[64];
    #pragma unroll
    for (int i = 0; i < 64; ++i) attsum[i] = 0.f;
    float Csc = 0.f;

    const float CEXP = (float)(1.4426950408889634 * 0.08838834764831845);

    const ushort* kbase = Kf + (size_t)t * 4096 + lane * 8;
    short8 kf[8];
    #pragma unroll
    for (int ks = 0; ks < 8; ++ks)
        kf[ks] = *(const short8*)(kbase + (size_t)wv * 32768 + ks * 512);

    int cnt = (wv == 0) ? 7 : 6;
    for (int mi = 0; mi < cnt; ++mi) {
        int m = wv + 4 * mi;

        f32x16 S;
        #pragma unroll
        for (int r = 0; r < 16; ++r) S[r] = 0.f;
        #pragma unroll
        for (int ks = 0; ks < 8; ++ks) {
            short8 qv = *(const short8*)(qls + ks * 512 + lane * 8);
            S = __builtin_amdgcn_mfma_f32_32x32x16_bf16(kf[ks], qv, S, 0, 0, 0);
        }

        float p[16], mx = -3e38f;
        #pragma unroll
        for (int r = 0; r < 16; ++r) {
            int key = (r & 3) + 8 * (r >> 2) + 4 * half;
            float v = (key < 25) ? S[r] : -3e38f;
            p[r] = v; mx = fmaxf(mx, v);
        }
        mx = fmaxf(mx, __shfl_xor(mx, 32));
        float sum = 0.f;
        #pragma unroll
        for (int r = 0; r < 16; ++r) { p[r] = exp2f((p[r] - mx) * CEXP); sum += p[r]; }
        sum += __shfl_xor(sum, 32);
        float inv = 1.f / sum;

        const ushort* vp = Vf + ((size_t)(m * 8 + t)) * 4096 + lane * 8;
        short8 vf0 = *(const short8*)(vp);
        short8 vf1 = *(const short8*)(vp + 512);
        short8 vf2 = *(const short8*)(vp + 1024);
        short8 vf3 = *(const short8*)(vp + 1536);
        short8 vf4 = *(const short8*)(vp + 2048);
        short8 vf5 = *(const short8*)(vp + 2560);
        short8 vf6 = *(const short8*)(vp + 3072);
        short8 vf7 = *(const short8*)(vp + 3584);
        #pragma unroll
        for (int ks = 0; ks < 8; ++ks)
            kf[ks] = *(const short8*)(kbase + (size_t)(m + 4) * 32768 + ks * 512);

        uint o01   = pkbf(p[0] * inv,  p[1] * inv);
        uint o23   = pkbf(p[2] * inv,  p[3] * inv);
        uint o45   = pkbf(p[4] * inv,  p[5] * inv);
        uint o67   = pkbf(p[6] * inv,  p[7] * inv);
        uint o89   = pkbf(p[8] * inv,  p[9] * inv);
        uint o1011 = pkbf(p[10] * inv, p[11] * inv);
        uint o1213 = pkbf(p[12] * inv, p[13] * inv);
        uint o1415 = pkbf(p[14] * inv, p[15] * inv);
        bool h0 = (half == 0);
        uint rA = __shfl_xor(h0 ? o45 : o01, 32);
        uint rB = __shfl_xor(h0 ? o67 : o23, 32);
        uint rC = __shfl_xor(h0 ? o1213 : o89, 32);
        uint rD = __shfl_xor(h0 ? o1415 : o1011, 32);
        pk_t P0, P1;
        P0.u4 = h0 ? make_uint4(o01, o23, rA, rB) : make_uint4(rA, rB, o45, o67);
        P1.u4 = h0 ? make_uint4(o89, o1011, rC, rD) : make_uint4(rC, rD, o1213, o1415);
        short8 pb0 = P0.s8, pb1 = P1.s8;

        f32x16 ctx[4];
        #pragma unroll
        for (int mt = 0; mt < 4; ++mt) {
            #pragma unroll
            for (int r = 0; r < 16; ++r) ctx[mt][r] = 0.f;
        }
        ctx[0] = __builtin_amdgcn_mfma_f32_32x32x16_bf16(vf0, pb0, ctx[0], 0, 0, 0);
        ctx[0] = __builtin_amdgcn_mfma_f32_32x32x16_bf16(vf1, pb1, ctx[0], 0, 0, 0);
        ctx[1] = __builtin_amdgcn_mfma_f32_32x32x16_bf16(vf2, pb0, ctx[1], 0, 0, 0);
        ctx[1] = __builtin_amdgcn_mfma_f32_32x32x16_bf16(vf3, pb1, ctx[1], 0, 0, 0);
        ctx[2] = __builtin_amdgcn_mfma_f32_32x32x16_bf16(vf4, pb0, ctx[2], 0, 0, 0);
        ctx[2] = __builtin_amdgcn_mfma_f32_32x32x16_bf16(vf5, pb1, ctx[2], 0, 0, 0);
        ctx[3] = __builtin_amdgcn_mfma_f32_32x32x16_bf16(vf6, pb0, ctx[3], 0, 0, 0);
        ctx[3] = __builtin_amdgcn_mfma_f32_32x32x16_bf16(vf7, pb1, ctx[3], 0, 0, 0);

        float s1 = 0.f, s2 = 0.f;
        #pragma unroll
        for (int mt = 0; mt < 4; ++mt) {
            float t1 = 0.f, t2 = 0.f;
            #pragma unroll
            for (int r = 0; r < 16; ++r) {
                int c = mt * 32 + (r & 3) + 8 * (r >> 2) + 4 * half;
                float xv = ctx[mt][r] + catb[qc * 129 + c];
                ctx[mt][r] = xv;
                t1 += xv; t2 = fmaf(xv, xv, t2);
            }
            s1 += t1; s2 += t2;
        }
        s1 += __shfl_xor(s1, 32); s2 += __shfl_xor(s2, 32);
        float mu = s1 * (1.f / 128.f);
        float var = s2 * (1.f / 128.f) - mu * mu;
        var = fmaxf(var, 0.f);
        float rs = rsqrtf(var + 1e-12f);
        #pragma unroll
        for (int i = 0; i < 64; ++i)
            attsum[i] = fmaf(ctx[i >> 4][i & 15], rs, attsum[i]);
        Csc = fmaf(-mu, rs, Csc);
    }

    __syncthreads();
    int s = half * 25 + q;
    bool act = q < 25;
    if ((wv == 1 || wv == 3) && act) {
        float (*rg)[65] = red[wv >> 1];
        #pragma unroll
        for (int i = 0; i < 64; ++i) rg[s][i] = attsum[i];
        rg[s][64] = Csc;
    }
    __syncthreads();
    if ((wv == 0 || wv == 2) && act) {
        float (*rg)[65] = red[wv >> 1];
        #pragma unroll
        for (int i = 0; i < 64; ++i) attsum[i] += rg[s][i];
        Csc += rg[s][64];
    }
    __syncthreads();
    if (wv == 2 && act) {
        #pragma unroll
        for (int i = 0; i < 64; ++i) red[0][s][i] = attsum[i];
        red[0][s][64] = Csc;
    }
    __syncthreads();
    if (wv == 0 && act) {
        #pragma unroll
        for (int i = 0; i < 64; ++i) attsum[i] += red[0][s][i];
        Csc += red[0][s][64];
        float* ap = att + (size_t)pair * TILE + q * 128;
        #pragma unroll
        for (int mt = 0; mt < 4; ++mt) {
            #pragma unroll
            for (int rg4 = 0; rg4 < 4; ++rg4) {
                int c0 = mt * 32 + 8 * rg4 + 4 * half;
                int i0 = mt * 16 + rg4 * 4;
                float4 o;
                o.x = attsum[i0 + 0] + Csc; o.y = attsum[i0 + 1] + Csc;
                o.z = attsum[i0 + 2] + Csc; o.w = attsum[i0 + 3] + Csc;
                *(float4*)&ap[c0] = o;
            }
        }
    }
}

// ============ kernel 3: fused distances + log-softmax loss/acc ============
__global__ __launch_bounds__(256) void k_dist_loss(
    const float* __restrict__ att, const float* __restrict__ ln_g,
    float* __restrict__ dist, int* __restrict__ counter,
    float* __restrict__ out) {
    int b = blockIdx.x;
    int i = b / 5, j = b - 5 * i;
    const float4* a  = (const float4*)(att + (size_t)i * ROW);
    const float4* s0 = (const float4*)(att + (size_t)(NQ + j * 5 + 0) * ROW);
    const float4* s1p = (const float4*)(att + (size_t)(NQ + j * 5 + 1) * ROW);
    const float4* s2p = (const float4*)(att + (size_t)(NQ + j * 5 + 2) * ROW);
    const float4* s3p = (const float4*)(att + (size_t)(NQ + j * 5 + 3) * ROW);
    const float4* s4p = (const float4*)(att + (size_t)(NQ + j * 5 + 4) * ROW);
    float d = 0.f;
    for (int e4 = threadIdx.x; e4 < 6400; e4 += 256) {
        float4 av = a[e4];
        float4 q0 = s0[e4], q1 = s1p[e4], q2 = s2p[e4], q3 = s3p[e4], q4 = s4p[e4];
        float4 g4 = *(const float4*)(ln_g + (e4 & 31) * 4);
        float px = 0.2f * (q0.x + q1.x + q2.x + q3.x + q4.x);
        float py = 0.2f * (q0.y + q1.y + q2.y + q3.y + q4.y);
        float pz = 0.2f * (q0.z + q1.z + q2.z + q3.z + q4.z);
        float pw = 0.2f * (q0.w + q1.w + q2.w + q3.w + q4.w);
        float dx = av.x - px, dy = av.y - py, dz = av.z - pz, dw = av.w - pw;
        d = fmaf(g4.x * g4.x, dx * dx, d);
        d = fmaf(g4.y * g4.y, dy * dy, d);
        d = fmaf(g4.z * g4.z, dz * dz, d);
        d = fmaf(g4.w * g4.w, dw * dw, d);
    }
    #pragma unroll
    for (int msk = 32; msk >= 1; msk >>= 1) d += __shfl_xor(d, msk);
    __shared__ float part[4];
    __shared__ int lastFlag;
    int lane = threadIdx.x & 63, wv = threadIdx.x >> 6;
    if (lane == 0) part[wv] = d;
    __syncthreads();
    if (threadIdx.x == 0) {
        float total = (part[0] + part[1] + part[2] + part[3]) * (1.f / 625.f);
        __hip_atomic_store(&dist[b], total, __ATOMIC_RELEASE, __HIP_MEMORY_SCOPE_AGENT);
        int tk = __hip_atomic_fetch_add(counter, 1, __ATOMIC_ACQ_REL, __HIP_MEMORY_SCOPE_AGENT);
        lastFlag = (tk == 374);
    }
    __syncthreads();
    if (!lastFlag) return;

    int iq = threadIdx.x;
    float li = 0.f, ok = 0.f;
    if (iq < NQ) {
        float dd[5];
        #pragma unroll
        for (int jj = 0; jj < 5; ++jj)
            dd[jj] = __hip_atomic_load(&dist[iq * 5 + jj], __ATOMIC_ACQUIRE, __HIP_MEMORY_SCOPE_AGENT);
        int cls = iq / NQRY;
        float mind = dd[0];
        int best = 0;
        #pragma unroll
        for (int jj = 1; jj < 5; ++jj) {
            if (dd[jj] < mind) mind = dd[jj];
            if (dd[jj] < dd[best]) best = jj;
        }
        float sume = 0.f;
        #pragma unroll
        for (int jj = 0; jj < 5; ++jj) sume += expf(mind - dd[jj]);
        float lse = logf(sume) - mind;
        li = dd[cls] + lse;
        ok = (best == cls) ? 1.f : 0.f;
    }
    #pragma unroll
    for (int msk = 32; msk >= 1; msk >>= 1) {
        li += __shfl_xor(li, msk);
        ok += __shfl_xor(ok, msk);
    }
    if (lane == 0) { part[wv] = li; part[wv + 2] = ok; }
    __syncthreads();
    if (threadIdx.x == 0) {
        out[0] = (part[0] + part[1]) / 75.f;
        out[1] = (part[2] + part[3]) / 75.f;
    }
}

extern "C" void kernel_launch(void* const* d_in, const int* in_sizes, int n_in,
                              void* d_out, int out_size, void* d_ws, size_t ws_size,
                              hipStream_t stream) {
    const float* input = (const float*)d_in[0];
    const float* Wq   = (const float*)d_in[1];
    const float* bq   = (const float*)d_in[2];
    const float* Wk   = (const float*)d_in[3];
    const float* bk   = (const float*)d_in[4];
    const float* Wv   = (const float*)d_in[5];
    const float* bv   = (const float*)d_in[6];
    const float* Wo   = (const float*)d_in[7];
    const float* bo   = (const float*)d_in[8];
    const float* ln_g = (const float*)d_in[9];
    const float* ln_b = (const float*)d_in[10];  // cancels in the distance
    const int* target = (const int*)d_in[11];
    float* out = (float*)d_out;
    (void)ln_b;

    float* ws = (float*)d_ws;
    ushort* catC = (ushort*)ws;                              // 2,560,000 u16
    ushort* Qf   = catC + 2560000;                           // 3,276,800
    ushort* Kf   = Qf + 3276800;                             //   819,200
    ushort* Vf   = Kf + 819200;                              //   819,200 (K prefetch overrun pad)
    float*  att  = (float*)(Vf + 819200);                    // 100*25600 fp32
    float*  distb = att + 2560000;                           // 375
    int*    counter = (int*)(distb + 512);
    // total ~25.2 MB

    k_proj<<<197, 256, 0, stream>>>(input, target, Wq, Wk, Wv, Wo, bq, bk, bv,
                                    catC, Qf, Kf, Vf, counter);
    k_attn<<<800, 256, 0, stream>>>(Qf, Kf, Vf, catC, bo, att);
    k_dist_loss<<<375, 256, 0, stream>>>(att, ln_g, distb, counter, out);
}

// Round 9
// 183.886 us; speedup vs baseline: 1.0173x; 1.0173x over previous
//
#include <hip/hip_runtime.h>
#include <math.h>

// Problem constants (fixed by reference setup_inputs)
#define NTOT 100
#define NQ   75
#define NP   25
#define CC   128
#define TT   8
#define VV   25
#define NCLS 5
#define NSUP 5
#define NQRY 15
#define ROW  (TT*VV*CC)   // 25600 floats per sample
#define TILE (VV*CC)      // 3200 floats per (n,t)
#define ROWS_Q 20000
#define ROWS_S 5000
#define RB_Q 625          // 20000/32 exact
#define RB_S 157          // ceil(5000/32)

typedef __attribute__((ext_vector_type(8))) short short8;
typedef __attribute__((ext_vector_type(16))) float f32x16;

typedef union { uint4 u4; short8 s8; } pk_t;

__device__ __forceinline__ ushort f2bf(float f) {
    uint u = __float_as_uint(f);
    u += 0x7FFFu + ((u >> 16) & 1u);   // RNE
    return (ushort)(u >> 16);
}
__device__ __forceinline__ float bf2f(uint u16v) {
    return __uint_as_float(u16v << 16);
}
__device__ __forceinline__ uint pkbf(float a, float b) {
    return (uint)f2bf(a) | ((uint)f2bf(b) << 16);
}

// ============ kernel 1: fused gather + projections ============
// One rowblock (32 tv-rows) per block; wave w computes output cols [32w,32w+32).
// blocks 0..624 : Q = cat@Wq+bq (also writes catC)
// blocks 625..781: K = supp@Wk+bk ; V = (supp@Wv+bv)@Wo
// A-rows staged once via LDS (coalesced), shared by all 4 waves.
__global__ __launch_bounds__(256) void k_proj(
    const float* __restrict__ input, const int* __restrict__ target,
    const float* __restrict__ Wq, const float* __restrict__ Wk,
    const float* __restrict__ Wv, const float* __restrict__ Wo,
    const float* __restrict__ bq, const float* __restrict__ bk,
    const float* __restrict__ bv,
    ushort* __restrict__ catC, ushort* __restrict__ Qf,
    ushort* __restrict__ Kf, ushort* __restrict__ Vf,
    int* __restrict__ counter) {
    __shared__ ushort stage[32 * 132];   // A rows bf16, stride-132 (2-way conflict free)
    __shared__ ushort Wf[16384];         // current W as B-frags (4 ct regions x 4096)
    __shared__ ushort VtF[4096];         // Vt A-frags (KV stage-2)
    __shared__ int iscr[200];            // sort scratch: [0..99] targets, [100..199] order

    int bid = blockIdx.x, tid = threadIdx.x;
    int w = tid >> 6, lane = tid & 63, half = lane >> 5, l31 = lane & 31;

    if (bid == 0 && tid == 0) *counter = 0;   // ticket for k_dist_loss

    // ---- inline stable rank-sort ----
    if (tid < NTOT) iscr[tid] = target[tid];
    __syncthreads();
    if (tid < NTOT) {
        int ti = iscr[tid], rank = 0;
        for (int j = 0; j < NTOT; ++j) {
            int tj = iscr[j];
            rank += (tj < ti) || (tj == ti && j < tid);
        }
        iscr[100 + rank] = tid;   // disjoint range from [0..99] reads
    }
    __syncthreads();

    bool isQ = bid < RB_Q;
    int rowblk = isQ ? bid : bid - RB_Q;
    int rlimit = isQ ? ROWS_Q : ROWS_S;
    int g0 = rowblk * 32;
    int gend = min(g0 + 32, rlimit);

    // ---- stage A rows [g0, gend) into LDS, coalesced (c-major, tv runs) ----
    for (int nn = g0 / 200; nn <= (gend - 1) / 200; ++nn) {
        int lo = max(g0 - nn * 200, 0);
        int hi = min(gend - 1 - nn * 200, 199);
        int len = hi - lo + 1;
        int nidx = isQ ? nn : (NQ + nn);
        int src;
        if (nidx < NQ) { int m = nidx / NQRY, qq = nidx - m * NQRY; src = iscr[100 + m * 20 + NSUP + qq]; }
        else           { int i2 = nidx - NQ; int m = i2 / NSUP, s = i2 - m * NSUP; src = iscr[100 + m * 20 + s]; }
        const float* inb = input + (size_t)src * ROW + lo;
        int rbase = nn * 200 + lo - g0;
        for (int idx = tid; idx < len * 128; idx += 256) {
            int c = idx / len, k = idx - c * len;
            stage[(rbase + k) * 132 + c] = f2bf(inb[c * 200 + k]);
        }
    }

    // ---- build W B-frags in LDS (cooperative, all 4 ct regions) ----
    #define BUILDW(W) do {                                                       \
        for (int o = tid; o < 2048; o += 256) {                                  \
            int k8 = o >> 7, c = o & 127;                                        \
            uint4 pk;                                                            \
            pk.x = pkbf((W)[(k8*8+0)*128 + c], (W)[(k8*8+1)*128 + c]);           \
            pk.y = pkbf((W)[(k8*8+2)*128 + c], (W)[(k8*8+3)*128 + c]);           \
            pk.z = pkbf((W)[(k8*8+4)*128 + c], (W)[(k8*8+5)*128 + c]);           \
            pk.w = pkbf((W)[(k8*8+6)*128 + c], (W)[(k8*8+7)*128 + c]);           \
            int dst = (((c >> 5) * 8 + (k8 >> 1)) * 64 + ((c & 31) + 32 * (k8 & 1))) * 8; \
            *(uint4*)(Wf + dst) = pk;                                            \
        }                                                                        \
    } while (0)

    BUILDW(isQ ? Wq : Wk);
    __syncthreads();

    // ---- A-frags from LDS stage (shared by all waves) ----
    short8 af[8];
    #pragma unroll
    for (int ks = 0; ks < 8; ++ks)
        af[ks] = *(const short8*)&stage[l31 * 132 + ks * 16 + half * 8];

    #define CHAIN(A, OUT) do {                                                   \
        const ushort* bp_ = Wf + w * 4096 + lane * 8;                            \
        _Pragma("unroll")                                                        \
        for (int ks = 0; ks < 8; ++ks) {                                         \
            short8 bf_ = *(const short8*)(bp_ + ks * 512);                       \
            OUT = __builtin_amdgcn_mfma_f32_32x32x16_bf16(A[ks], bf_, OUT, 0, 0, 0); \
        }                                                                        \
    } while (0)

    if (isQ) {
        f32x16 Cm;
        #pragma unroll
        for (int r = 0; r < 16; ++r) Cm[r] = 0.f;
        CHAIN(af, Cm);
        float bcol = bq[w * 32 + l31];
        int c = w * 32 + l31;
        #pragma unroll
        for (int r = 0; r < 16; ++r) {
            int row = g0 + (r & 3) + 8 * (r >> 2) + 4 * half;   // all Q rows valid
            int st = row / 25, vv = row - st * 25;
            size_t dst = (((size_t)st * 8 + (c >> 4)) * 64 + (vv + 32 * ((c >> 3) & 1))) * 8 + (c & 7);
            Qf[dst] = f2bf(Cm[r] + bcol);
        }
        // catC bf16 [row][c] cooperatively from stage
        uint* cc = (uint*)catC + (size_t)g0 * 64;
        for (int idx = tid; idx < 2048; idx += 256) {
            int row = idx >> 6, c2 = (idx & 63) * 2;
            cc[idx] = (uint)stage[row * 132 + c2] | ((uint)stage[row * 132 + c2 + 1] << 16);
        }
    } else {
        // ---- K ----
        {
            f32x16 Cm;
            #pragma unroll
            for (int r = 0; r < 16; ++r) Cm[r] = 0.f;
            CHAIN(af, Cm);
            float bcol = bk[w * 32 + l31];
            int c = w * 32 + l31;
            #pragma unroll
            for (int r = 0; r < 16; ++r) {
                int row = g0 + (r & 3) + 8 * (r >> 2) + 4 * half;
                if (row < ROWS_S) {
                    int st = row / 25, vv = row - st * 25;
                    size_t dst = (((size_t)st * 8 + (c >> 4)) * 64 + (vv + 32 * ((c >> 3) & 1))) * 8 + (c & 7);
                    Kf[dst] = f2bf(Cm[r] + bcol);
                }
            }
        }
        __syncthreads();   // Wk frag reads done
        // ---- Vt = supp@Wv + bv -> A-frags in VtF ----
        BUILDW(Wv);
        __syncthreads();
        {
            f32x16 Cm;
            #pragma unroll
            for (int r = 0; r < 16; ++r) Cm[r] = 0.f;
            CHAIN(af, Cm);
            float bcol = bv[w * 32 + l31];
            int c = w * 32 + l31;
            int ks2 = c >> 4, kh = (c >> 3) & 1, j2 = c & 7;
            #pragma unroll
            for (int r = 0; r < 16; ++r) {
                int rowLocal = (r & 3) + 8 * (r >> 2) + 4 * half;
                VtF[ks2 * 512 + (rowLocal + 32 * kh) * 8 + j2] = f2bf(Cm[r] + bcol);
            }
        }
        __syncthreads();   // VtF written; Wv frag reads done
        // ---- V = Vt @ Wo -> Vf frags ----
        BUILDW(Wo);
        __syncthreads();
        short8 a2[8];
        #pragma unroll
        for (int ks = 0; ks < 8; ++ks)
            a2[ks] = *(const short8*)&VtF[ks * 512 + lane * 8];
        {
            f32x16 Cm;
            #pragma unroll
            for (int r = 0; r < 16; ++r) Cm[r] = 0.f;
            CHAIN(a2, Cm);
            int c = w * 32 + l31;
            #pragma unroll
            for (int r = 0; r < 16; ++r) {
                int row = g0 + (r & 3) + 8 * (r >> 2) + 4 * half;
                if (row < ROWS_S) {
                    int tile = row / 25, vv = row - tile * 25;
                    size_t dst = ((((size_t)tile * 4 + (c >> 5)) * 2 + (vv >> 4)) * 64
                                  + ((c & 31) + 32 * ((vv & 15) >> 3))) * 8 + (vv & 7);
                    Vf[dst] = f2bf(Cm[r]);
                }
            }
        }
    }
    #undef CHAIN
    #undef BUILDW
}

// ============ kernel 2: MFMA fused attention + residual + LN ============
// (byte-identical to R7/R8: 800 blocks, shuffle-based P transpose)
__global__ __launch_bounds__(256, 2) void k_attn(
    const ushort* __restrict__ Qf, const ushort* __restrict__ Kf,
    const ushort* __restrict__ Vf, const ushort* __restrict__ catC,
    const float* __restrict__ bo, float* __restrict__ att) {
    __shared__ float catb[25 * 129];
    __shared__ float red[2][50][65];
    __shared__ ushort qls[4096];

    int pair = blockIdx.x;                    // n*8 + t
    int t = pair & 7;
    int tid = threadIdx.x;
    int wv = tid >> 6, lane = tid & 63;
    int q = lane & 31, half = lane >> 5;

    {
        const uint* cc = (const uint*)catC + (size_t)pair * 1600;
        for (int i2 = tid; i2 < 1600; i2 += 256) {
            uint u = cc[i2];
            int r = i2 >> 6, c2 = (i2 & 63) * 2;
            catb[r * 129 + c2]     = bf2f(u & 0xffffu) + bo[c2];
            catb[r * 129 + c2 + 1] = bf2f(u >> 16) + bo[c2 + 1];
        }
    }
    {
        const uint* qp = (const uint*)(Qf + (size_t)pair * 4096);
        uint* ql = (uint*)qls;
        for (int i2 = tid; i2 < 2048; i2 += 256) ql[i2] = qp[i2];
    }
    __syncthreads();

    int qc = q < 25 ? q : 24;
    float attsum[64];
    #pragma unroll
    for (int i = 0; i < 64; ++i) attsum[i] = 0.f;
    float Csc = 0.f;

    const float CEXP = (float)(1.4426950408889634 * 0.08838834764831845);

    const ushort* kbase = Kf + (size_t)t * 4096 + lane * 8;
    short8 kf[8];
    #pragma unroll
    for (int ks = 0; ks < 8; ++ks)
        kf[ks] = *(const short8*)(kbase + (size_t)wv * 32768 + ks * 512);

    int cnt = (wv == 0) ? 7 : 6;
    for (int mi = 0; mi < cnt; ++mi) {
        int m = wv + 4 * mi;

        f32x16 S;
        #pragma unroll
        for (int r = 0; r < 16; ++r) S[r] = 0.f;
        #pragma unroll
        for (int ks = 0; ks < 8; ++ks) {
            short8 qv = *(const short8*)(qls + ks * 512 + lane * 8);
            S = __builtin_amdgcn_mfma_f32_32x32x16_bf16(kf[ks], qv, S, 0, 0, 0);
        }

        float p[16], mx = -3e38f;
        #pragma unroll
        for (int r = 0; r < 16; ++r) {
            int key = (r & 3) + 8 * (r >> 2) + 4 * half;
            float v = (key < 25) ? S[r] : -3e38f;
            p[r] = v; mx = fmaxf(mx, v);
        }
        mx = fmaxf(mx, __shfl_xor(mx, 32));
        float sum = 0.f;
        #pragma unroll
        for (int r = 0; r < 16; ++r) { p[r] = exp2f((p[r] - mx) * CEXP); sum += p[r]; }
        sum += __shfl_xor(sum, 32);
        float inv = 1.f / sum;

        const ushort* vp = Vf + ((size_t)(m * 8 + t)) * 4096 + lane * 8;
        short8 vf0 = *(const short8*)(vp);
        short8 vf1 = *(const short8*)(vp + 512);
        short8 vf2 = *(const short8*)(vp + 1024);
        short8 vf3 = *(const short8*)(vp + 1536);
        short8 vf4 = *(const short8*)(vp + 2048);
        short8 vf5 = *(const short8*)(vp + 2560);
        short8 vf6 = *(const short8*)(vp + 3072);
        short8 vf7 = *(const short8*)(vp + 3584);
        #pragma unroll
        for (int ks = 0; ks < 8; ++ks)
            kf[ks] = *(const short8*)(kbase + (size_t)(m + 4) * 32768 + ks * 512);

        uint o01   = pkbf(p[0] * inv,  p[1] * inv);
        uint o23   = pkbf(p[2] * inv,  p[3] * inv);
        uint o45   = pkbf(p[4] * inv,  p[5] * inv);
        uint o67   = pkbf(p[6] * inv,  p[7] * inv);
        uint o89   = pkbf(p[8] * inv,  p[9] * inv);
        uint o1011 = pkbf(p[10] * inv, p[11] * inv);
        uint o1213 = pkbf(p[12] * inv, p[13] * inv);
        uint o1415 = pkbf(p[14] * inv, p[15] * inv);
        bool h0 = (half == 0);
        uint rA = __shfl_xor(h0 ? o45 : o01, 32);
        uint rB = __shfl_xor(h0 ? o67 : o23, 32);
        uint rC = __shfl_xor(h0 ? o1213 : o89, 32);
        uint rD = __shfl_xor(h0 ? o1415 : o1011, 32);
        pk_t P0, P1;
        P0.u4 = h0 ? make_uint4(o01, o23, rA, rB) : make_uint4(rA, rB, o45, o67);
        P1.u4 = h0 ? make_uint4(o89, o1011, rC, rD) : make_uint4(rC, rD, o1213, o1415);
        short8 pb0 = P0.s8, pb1 = P1.s8;

        f32x16 ctx[4];
        #pragma unroll
        for (int mt = 0; mt < 4; ++mt) {
            #pragma unroll
            for (int r = 0; r < 16; ++r) ctx[mt][r] = 0.f;
        }
        ctx[0] = __builtin_amdgcn_mfma_f32_32x32x16_bf16(vf0, pb0, ctx[0], 0, 0, 0);
        ctx[0] = __builtin_amdgcn_mfma_f32_32x32x16_bf16(vf1, pb1, ctx[0], 0, 0, 0);
        ctx[1] = __builtin_amdgcn_mfma_f32_32x32x16_bf16(vf2, pb0, ctx[1], 0, 0, 0);
        ctx[1] = __builtin_amdgcn_mfma_f32_32x32x16_bf16(vf3, pb1, ctx[1], 0, 0, 0);
        ctx[2] = __builtin_amdgcn_mfma_f32_32x32x16_bf16(vf4, pb0, ctx[2], 0, 0, 0);
        ctx[2] = __builtin_amdgcn_mfma_f32_32x32x16_bf16(vf5, pb1, ctx[2], 0, 0, 0);
        ctx[3] = __builtin_amdgcn_mfma_f32_32x32x16_bf16(vf6, pb0, ctx[3], 0, 0, 0);
        ctx[3] = __builtin_amdgcn_mfma_f32_32x32x16_bf16(vf7, pb1, ctx[3], 0, 0, 0);

        float s1 = 0.f, s2 = 0.f;
        #pragma unroll
        for (int mt = 0; mt < 4; ++mt) {
            float t1 = 0.f, t2 = 0.f;
            #pragma unroll
            for (int r = 0; r < 16; ++r) {
                int c = mt * 32 + (r & 3) + 8 * (r >> 2) + 4 * half;
                float xv = ctx[mt][r] + catb[qc * 129 + c];
                ctx[mt][r] = xv;
                t1 += xv; t2 = fmaf(xv, xv, t2);
            }
            s1 += t1; s2 += t2;
        }
        s1 += __shfl_xor(s1, 32); s2 += __shfl_xor(s2, 32);
        float mu = s1 * (1.f / 128.f);
        float var = s2 * (1.f / 128.f) - mu * mu;
        var = fmaxf(var, 0.f);
        float rs = rsqrtf(var + 1e-12f);
        #pragma unroll
        for (int i = 0; i < 64; ++i)
            attsum[i] = fmaf(ctx[i >> 4][i & 15], rs, attsum[i]);
        Csc = fmaf(-mu, rs, Csc);
    }

    __syncthreads();
    int s = half * 25 + q;
    bool act = q < 25;
    if ((wv == 1 || wv == 3) && act) {
        float (*rg)[65] = red[wv >> 1];
        #pragma unroll
        for (int i = 0; i < 64; ++i) rg[s][i] = attsum[i];
        rg[s][64] = Csc;
    }
    __syncthreads();
    if ((wv == 0 || wv == 2) && act) {
        float (*rg)[65] = red[wv >> 1];
        #pragma unroll
        for (int i = 0; i < 64; ++i) attsum[i] += rg[s][i];
        Csc += rg[s][64];
    }
    __syncthreads();
    if (wv == 2 && act) {
        #pragma unroll
        for (int i = 0; i < 64; ++i) red[0][s][i] = attsum[i];
        red[0][s][64] = Csc;
    }
    __syncthreads();
    if (wv == 0 && act) {
        #pragma unroll
        for (int i = 0; i < 64; ++i) attsum[i] += red[0][s][i];
        Csc += red[0][s][64];
        float* ap = att + (size_t)pair * TILE + q * 128;
        #pragma unroll
        for (int mt = 0; mt < 4; ++mt) {
            #pragma unroll
            for (int rg4 = 0; rg4 < 4; ++rg4) {
                int c0 = mt * 32 + 8 * rg4 + 4 * half;
                int i0 = mt * 16 + rg4 * 4;
                float4 o;
                o.x = attsum[i0 + 0] + Csc; o.y = attsum[i0 + 1] + Csc;
                o.z = attsum[i0 + 2] + Csc; o.w = attsum[i0 + 3] + Csc;
                *(float4*)&ap[c0] = o;
            }
        }
    }
}

// ============ kernel 3: fused distances + log-softmax loss/acc ============
__global__ __launch_bounds__(256) void k_dist_loss(
    const float* __restrict__ att, const float* __restrict__ ln_g,
    float* __restrict__ dist, int* __restrict__ counter,
    float* __restrict__ out) {
    int b = blockIdx.x;
    int i = b / 5, j = b - 5 * i;
    const float4* a  = (const float4*)(att + (size_t)i * ROW);
    const float4* s0 = (const float4*)(att + (size_t)(NQ + j * 5 + 0) * ROW);
    const float4* s1p = (const float4*)(att + (size_t)(NQ + j * 5 + 1) * ROW);
    const float4* s2p = (const float4*)(att + (size_t)(NQ + j * 5 + 2) * ROW);
    const float4* s3p = (const float4*)(att + (size_t)(NQ + j * 5 + 3) * ROW);
    const float4* s4p = (const float4*)(att + (size_t)(NQ + j * 5 + 4) * ROW);
    float d = 0.f;
    for (int e4 = threadIdx.x; e4 < 6400; e4 += 256) {
        float4 av = a[e4];
        float4 q0 = s0[e4], q1 = s1p[e4], q2 = s2p[e4], q3 = s3p[e4], q4 = s4p[e4];
        float4 g4 = *(const float4*)(ln_g + (e4 & 31) * 4);
        float px = 0.2f * (q0.x + q1.x + q2.x + q3.x + q4.x);
        float py = 0.2f * (q0.y + q1.y + q2.y + q3.y + q4.y);
        float pz = 0.2f * (q0.z + q1.z + q2.z + q3.z + q4.z);
        float pw = 0.2f * (q0.w + q1.w + q2.w + q3.w + q4.w);
        float dx = av.x - px, dy = av.y - py, dz = av.z - pz, dw = av.w - pw;
        d = fmaf(g4.x * g4.x, dx * dx, d);
        d = fmaf(g4.y * g4.y, dy * dy, d);
        d = fmaf(g4.z * g4.z, dz * dz, d);
        d = fmaf(g4.w * g4.w, dw * dw, d);
    }
    #pragma unroll
    for (int msk = 32; msk >= 1; msk >>= 1) d += __shfl_xor(d, msk);
    __shared__ float part[4];
    __shared__ int lastFlag;
    int lane = threadIdx.x & 63, wv = threadIdx.x >> 6;
    if (lane == 0) part[wv] = d;
    __syncthreads();
    if (threadIdx.x == 0) {
        float total = (part[0] + part[1] + part[2] + part[3]) * (1.f / 625.f);
        __hip_atomic_store(&dist[b], total, __ATOMIC_RELEASE, __HIP_MEMORY_SCOPE_AGENT);
        int tk = __hip_atomic_fetch_add(counter, 1, __ATOMIC_ACQ_REL, __HIP_MEMORY_SCOPE_AGENT);
        lastFlag = (tk == 374);
    }
    __syncthreads();
    if (!lastFlag) return;

    int iq = threadIdx.x;
    float li = 0.f, ok = 0.f;
    if (iq < NQ) {
        float dd[5];
        #pragma unroll
        for (int jj = 0; jj < 5; ++jj)
            dd[jj] = __hip_atomic_load(&dist[iq * 5 + jj], __ATOMIC_ACQUIRE, __HIP_MEMORY_SCOPE_AGENT);
        int cls = iq / NQRY;
        float mind = dd[0];
        int best = 0;
        #pragma unroll
        for (int jj = 1; jj < 5; ++jj) {
            if (dd[jj] < mind) mind = dd[jj];
            if (dd[jj] < dd[best]) best = jj;
        }
        float sume = 0.f;
        #pragma unroll
        for (int jj = 0; jj < 5; ++jj) sume += expf(mind - dd[jj]);
        float lse = logf(sume) - mind;
        li = dd[cls] + lse;
        ok = (best == cls) ? 1.f : 0.f;
    }
    #pragma unroll
    for (int msk = 32; msk >= 1; msk >>= 1) {
        li += __shfl_xor(li, msk);
        ok += __shfl_xor(ok, msk);
    }
    if (lane == 0) { part[wv] = li; part[wv + 2] = ok; }
    __syncthreads();
    if (threadIdx.x == 0) {
        out[0] = (part[0] + part[1]) / 75.f;
        out[1] = (part[2] + part[3]) / 75.f;
    }
}

extern "C" void kernel_launch(void* const* d_in, const int* in_sizes, int n_in,
                              void* d_out, int out_size, void* d_ws, size_t ws_size,
                              hipStream_t stream) {
    const float* input = (const float*)d_in[0];
    const float* Wq   = (const float*)d_in[1];
    const float* bq   = (const float*)d_in[2];
    const float* Wk   = (const float*)d_in[3];
    const float* bk   = (const float*)d_in[4];
    const float* Wv   = (const float*)d_in[5];
    const float* bv   = (const float*)d_in[6];
    const float* Wo   = (const float*)d_in[7];
    const float* bo   = (const float*)d_in[8];
    const float* ln_g = (const float*)d_in[9];
    const float* ln_b = (const float*)d_in[10];  // cancels in the distance
    const int* target = (const int*)d_in[11];
    float* out = (float*)d_out;
    (void)ln_b;

    float* ws = (float*)d_ws;
    ushort* catC = (ushort*)ws;                              // 2,560,000 u16
    ushort* Qf   = catC + 2560000;                           // 3,276,800
    ushort* Kf   = Qf + 3276800;                             //   819,200
    ushort* Vf   = Kf + 819200;                              //   819,200 (K prefetch overrun pad)
    float*  att  = (float*)(Vf + 819200);                    // 100*25600 fp32
    float*  distb = att + 2560000;                           // 375
    int*    counter = (int*)(distb + 512);
    // total ~25.2 MB

    k_proj<<<RB_Q + RB_S, 256, 0, stream>>>(input, target, Wq, Wk, Wv, Wo, bq, bk, bv,
                                            catC, Qf, Kf, Vf, counter);
    k_attn<<<800, 256, 0, stream>>>(Qf, Kf, Vf, catC, bo, att);
    k_dist_loss<<<375, 256, 0, stream>>>(att, ln_g, distb, counter, out);
}